// Round 7
// baseline (107.574 us; speedup 1.0000x reference)
//
#include <hip/hip_runtime.h>
#include <math.h>

// DIN fused pipeline, round 7: kT-only LDS (28.8 KB -> 5 blocks/CU).
//  prep: [blocks 0..2047] convert embT/embR/Wk f32->bf16 ; [2048..2303] q/u/targ bf16
//  B: per (batch,half): A-fragments loaded DIRECTLY from bf16 tables (L2-resident,
//     no LDS hist staging); k-GEMM (MFMA) -> plain bf16 stores into kT[j][e_l]
//     (bijection f=200e+j, every slot written once, no RMW/atomics);
//     hdot/tdot fused as extra MFMA vs on-demand [u|t] B-operand;
//     scores = q-slice x kT rows via second MFMA.
//  F: sum halves, masked exp, beta=0.5 norm, pred, sigmoid

#define HH 200
#define EE 128
#define KT_PITCH 72   // u16/row = 144 B: 16B-aligned rows, balanced banks on b128 reads

typedef float fp32x4 __attribute__((ext_vector_type(4)));
typedef short bf16x8 __attribute__((ext_vector_type(8)));

static __device__ __forceinline__ unsigned short f2bf(float x) {
    unsigned u = __builtin_bit_cast(unsigned, x);
    unsigned r = (u + 0x7FFFu + ((u >> 16) & 1u)) >> 16;   // RNE
    return (unsigned short)r;
}

// ---------------- Kernel prep: table conversion + q/u/targ projection ----------------
#define N4_T 1600000   // embT float4 units (100000*64/4)
#define N4_R 16000     // embR
#define N4_K 4096      // Wk
#define N4_ALL (N4_T + N4_R + N4_K)
#define CONV_BLOCKS 2048
#define CONV_THREADS (CONV_BLOCKS * 256)

__global__ __launch_bounds__(256) void prep(
    const int* __restrict__ target, const int* __restrict__ tregion,
    const float* __restrict__ embT, const float* __restrict__ embR,
    const float* __restrict__ Wq, const float* __restrict__ Wk,
    const float* __restrict__ Wv,
    unsigned short* __restrict__ dT, unsigned short* __restrict__ dR,
    unsigned short* __restrict__ dK,
    unsigned short* __restrict__ qbf, unsigned short* __restrict__ ubf,
    unsigned short* __restrict__ tbf)
{
    const int tid = threadIdx.x;
    if (blockIdx.x < CONV_BLOCKS) {
        int idx = blockIdx.x * 256 + tid;
        for (int i = idx; i < N4_ALL; i += CONV_THREADS) {
            const float* src; unsigned short* dst;
            if (i < N4_T)             { src = embT + 4*(size_t)i;            dst = dT + 4*(size_t)i; }
            else if (i < N4_T + N4_R) { int j = i - N4_T;        src = embR + 4*(size_t)j; dst = dR + 4*(size_t)j; }
            else                      { int j = i - N4_T - N4_R; src = Wk   + 4*(size_t)j; dst = dK + 4*(size_t)j; }
            float4 v = *(const float4*)src;
            ushort4 o;
            o.x = f2bf(v.x); o.y = f2bf(v.y); o.z = f2bf(v.z); o.w = f2bf(v.w);
            *(ushort4*)dst = o;
        }
        return;
    }

    // projection role: 8 batches per block
    __shared__ float st[8][128];
    const int b0 = (blockIdx.x - CONV_BLOCKS) * 8;

    if (tid < 128) {
        int bb = tid >> 4, j = tid & 15;
        int b = b0 + bb;
        int ti = target[b], ri = tregion[b];
        *(float4*)&st[bb][j*4]      = *(const float4*)(embT + (size_t)ti*64 + j*4);
        *(float4*)&st[bb][64+j*4]   = *(const float4*)(embR + (size_t)ri*64 + j*4);
    }
    __syncthreads();

    if (tid < 128) {
        float acc[8] = {0,0,0,0,0,0,0,0};
        const float4* wr = (const float4*)(Wq + (size_t)tid*128);
        for (int e4 = 0; e4 < 32; e4++) {
            float4 w4 = wr[e4];
            #pragma unroll
            for (int bb = 0; bb < 8; bb++) {
                float4 t4 = *(const float4*)&st[bb][e4*4];
                acc[bb] += w4.x*t4.x + w4.y*t4.y + w4.z*t4.z + w4.w*t4.w;
            }
        }
        #pragma unroll
        for (int bb = 0; bb < 8; bb++) qbf[(size_t)(b0+bb)*128 + tid] = f2bf(acc[bb]);
    } else {
        int e = tid - 128;
        float acc[8] = {0,0,0,0,0,0,0,0};
        for (int f = 0; f < 128; f++) {
            float wv = Wv[(size_t)f*128 + e];
            #pragma unroll
            for (int bb = 0; bb < 8; bb++) acc[bb] += st[bb][f] * wv;
        }
        #pragma unroll
        for (int bb = 0; bb < 8; bb++) ubf[(size_t)(b0+bb)*128 + e] = f2bf(acc[bb]);
    }
    __syncthreads();
    {
        int bb = tid >> 5, x = (tid & 31) * 4;
        float4 t4 = *(const float4*)&st[bb][x];
        ushort4 o; o.x = f2bf(t4.x); o.y = f2bf(t4.y); o.z = f2bf(t4.z); o.w = f2bf(t4.w);
        *(ushort4*)&tbf[(size_t)(b0+bb)*128 + x] = o;
    }
}

// ---------------- Kernel B: direct-gather k-GEMM -> kT -> scores/hdot/tdot ----------------
// grid 4096: b = bid>>1, hf = bid&1.  LDS = 28.8 KB -> 5 blocks/CU.
__global__ __launch_bounds__(256, 5) void hist_gemm(
    const int* __restrict__ history, const int* __restrict__ hregion,
    const unsigned short* __restrict__ eT, const unsigned short* __restrict__ eR,
    const unsigned short* __restrict__ wk, const unsigned short* __restrict__ qb,
    const unsigned short* __restrict__ ub, const unsigned short* __restrict__ tb,
    float* __restrict__ scores_p, float* __restrict__ hdot, float* __restrict__ tdot)
{
    __shared__ unsigned short kT[200*KT_PITCH];   // kT[j][e_l], e_l = f/200 - 64*hf

    const int bid = blockIdx.x;
    const int b = bid >> 1, hf = bid & 1;
    const int tid = threadIdx.x;
    const int lane = tid & 63, w = tid >> 6;
    const int c = lane & 15, g = lane >> 4;
    const int e0 = 8 * g;
    const int rbase = hf * 100;

    // Wk B-fragments: wave w owns k-columns h in [32w, 32w+32)
    bf16x8 wkf[2][4];
    #pragma unroll
    for (int nt = 0; nt < 2; nt++)
        #pragma unroll
        for (int kc = 0; kc < 4; kc++)
            wkf[nt][kc] = *(const bf16x8*)(wk + (size_t)(32*w + 16*nt + c)*128 + kc*32 + e0);

    // per-thread row indices for this lane's A rows (row = r0(mt) + c)
    int ihx[7], irx[7];
    #pragma unroll
    for (int mt = 0; mt < 7; mt++) {
        const int r0 = (mt < 6) ? mt*16 : 84;     // mt6 re-covers 84..99 (no OOB)
        size_t rg = (size_t)b*200 + rbase + r0 + c;
        ihx[mt] = history[rg];
        irx[mt] = hregion[rg];
    }

    // k-GEMM: A-fragments straight from bf16 tables; plain bf16 stores into kT.
    #pragma unroll 1
    for (int mt = 0; mt < 7; mt++) {
        const int r0 = (mt < 6) ? mt*16 : 84;
        const unsigned short* tRow = eT + (size_t)ihx[mt]*64;
        const unsigned short* rRow = eR + (size_t)irx[mt]*64;
        bf16x8 a[4];
        a[0] = *(const bf16x8*)(tRow + e0);
        a[1] = *(const bf16x8*)(tRow + 32 + e0);
        a[2] = *(const bf16x8*)(rRow + e0);
        a[3] = *(const bf16x8*)(rRow + 32 + e0);

        fp32x4 acc0 = {0,0,0,0}, acc1 = {0,0,0,0};
        #pragma unroll
        for (int kc = 0; kc < 4; kc++) {
            acc0 = __builtin_amdgcn_mfma_f32_16x16x32_bf16(a[kc], wkf[0][kc], acc0, 0, 0, 0);
            acc1 = __builtin_amdgcn_mfma_f32_16x16x32_bf16(a[kc], wkf[1][kc], acc1, 0, 0, 0);
        }
        const int slb = r0 + 4*g;
        #pragma unroll
        for (int r = 0; r < 4; r++) {
            unsigned f  = (unsigned)((rbase + slb + r)*128 + 32*w + c);
            unsigned e  = f / 200u;  unsigned j  = f - e*200u;
            kT[j*KT_PITCH + (e - (unsigned)(hf<<6))] = f2bf(acc0[r]);
            unsigned f2 = f + 16u;
            unsigned e2 = f2 / 200u; unsigned j2 = f2 - e2*200u;
            kT[j2*KT_PITCH + (e2 - (unsigned)(hf<<6))] = f2bf(acc1[r]);
        }
        // fused hdot/tdot: extra MFMA vs on-demand [u|t] packed B (cols 0-7=u, 8-15=t)
        if ((mt & 3) == w) {
            const unsigned short* utp = (c < 8 ? ub : tb) + (size_t)b*128;
            fp32x4 hacc = {0,0,0,0};
            #pragma unroll
            for (int kc = 0; kc < 4; kc++) {
                bf16x8 utf = *(const bf16x8*)(utp + kc*32 + e0);
                hacc = __builtin_amdgcn_mfma_f32_16x16x32_bf16(a[kc], utf, hacc, 0, 0, 0);
            }
            if (c == 0 || c == 8) {
                float* dst = (c == 0) ? hdot : tdot;
                #pragma unroll
                for (int r = 0; r < 4; r++)
                    dst[(size_t)b*200 + rbase + slb + r] = hacc[r];
            }
        }
    }
    __syncthreads();

    // scores = q-slice (bf16) x kT rows via MFMA; 13 j-tiles round-robined to waves
    for (int jt = w; jt < 13; jt += 4) {
        int jr = jt*16 + c; if (jr > 199) jr = 199;   // pad rows discarded below
        fp32x4 sacc = {0,0,0,0};
        #pragma unroll
        for (int kc = 0; kc < 2; kc++) {
            bf16x8 af  = *(const bf16x8*)(qb + (size_t)b*128 + (hf<<6) + kc*32 + e0);
            bf16x8 bfr = *(const bf16x8*)&kT[(unsigned)jr*KT_PITCH + kc*32 + e0];
            sacc = __builtin_amdgcn_mfma_f32_16x16x32_bf16(af, bfr, sacc, 0, 0, 0);
        }
        if (lane < 16) {
            int j = jt*16 + lane;
            if (j < 200) scores_p[(size_t)bid*200 + j] = sacc[0];
        }
    }
}

// ---------------- Kernel F: finalize (8 batches/block) ----------------
__global__ __launch_bounds__(256) void finalize_k(
    const int* __restrict__ history, const int* __restrict__ target,
    const float* __restrict__ hvr,
    const float* __restrict__ scores_p, const float* __restrict__ hdot,
    const float* __restrict__ tdot, float* __restrict__ out)
{
    const int tid = threadIdx.x, lane = tid & 63, w = tid >> 6;
    #pragma unroll
    for (int bb = 0; bb < 2; bb++) {
        int b = blockIdx.x*8 + w*2 + bb;
        int tgt = target[b];
        float ev[4], hd[4], td[4], hv[4];
        #pragma unroll
        for (int i = 0; i < 4; i++) {
            int j = lane + i*64;
            if (j < 200) {
                float sc = scores_p[(size_t)(2*b)*200 + j] + scores_p[(size_t)(2*b+1)*200 + j];
                int uh = history[(size_t)b*200 + j];
                ev[i] = (uh != tgt) ? expf(sc * 0.088388347648318447f) : 0.f;
                hd[i] = hdot[(size_t)b*200 + j];
                td[i] = tdot[(size_t)b*200 + j];
                hv[i] = hvr[j];
            } else { ev[i] = 0.f; hd[i] = 0.f; td[i] = 0.f; hv[i] = 0.f; }
        }
        float tot = (ev[0]+ev[1]) + (ev[2]+ev[3]);
        #pragma unroll
        for (int m = 1; m < 64; m <<= 1) tot += __shfl_xor(tot, m, 64);
        float inv = rsqrtf(tot);          // exp_A / sum^0.5
        float p = 0.f;
        #pragma unroll
        for (int i = 0; i < 4; i++) p += ev[i]*inv*hd[i] + hv[i]*td[i];
        #pragma unroll
        for (int m = 1; m < 64; m <<= 1) p += __shfl_xor(p, m, 64);
        if (lane == 0) out[b] = 1.0f / (1.0f + expf(-p));
    }
}

extern "C" void kernel_launch(void* const* d_in, const int* in_sizes, int n_in,
                              void* d_out, int out_size, void* d_ws, size_t ws_size,
                              hipStream_t stream) {
    const int*   history = (const int*)d_in[0];
    const int*   target  = (const int*)d_in[1];
    const int*   hregion = (const int*)d_in[2];
    const int*   tregion = (const int*)d_in[3];
    const float* hvrate  = (const float*)d_in[4];
    const float* embT    = (const float*)d_in[5];
    const float* embR    = (const float*)d_in[6];
    const float* Wq      = (const float*)d_in[7];
    const float* Wk      = (const float*)d_in[8];
    const float* Wv      = (const float*)d_in[9];
    float* outp = (float*)d_out;

    char* ws = (char*)d_ws;
    unsigned short* dT = (unsigned short*)(ws);                 // 12,800,000 B
    unsigned short* dR = (unsigned short*)(ws + 12800000);      //    128,000
    unsigned short* dK = (unsigned short*)(ws + 12928000);      //     32,768
    unsigned short* ub = (unsigned short*)(ws + 12960768);      //    524,288
    unsigned short* tb = (unsigned short*)(ws + 13485056);      //    524,288
    unsigned short* qb = (unsigned short*)(ws + 14009344);      //    524,288
    float* sp          = (float*)(ws + 14533632);               //  3,276,800
    float* hdp         = (float*)(ws + 17810432);               //  1,638,400
    float* tdp         = (float*)(ws + 19448832);               //  1,638,400  (end 21,087,232)

    hipLaunchKernelGGL(prep, dim3(CONV_BLOCKS + 256), dim3(256), 0, stream,
                       target, tregion, embT, embR, Wq, Wk, Wv,
                       dT, dR, dK, qb, ub, tb);
    hipLaunchKernelGGL(hist_gemm, dim3(4096), dim3(256), 0, stream,
                       history, hregion, dT, dR, dK, qb, ub, tb, sp, hdp, tdp);
    hipLaunchKernelGGL(finalize_k, dim3(256), dim3(256), 0, stream,
                       history, target, hvrate, sp, hdp, tdp, outp);
}

// Round 8
// 88.613 us; speedup vs baseline: 1.2140x; 1.2140x over previous
//
#include <hip/hip_runtime.h>
#include <math.h>

// DIN fused pipeline, round 8: LDS overlay (hist tile THEN kT in the same 28.8 KB).
//  prep: [blocks 0..2047] convert embT/embR/Wk f32->bf16 ; [2048..2303] q/u/targ bf16
//  B: per (batch,half):
//     G: gather 112 clamped hist rows -> swizzled LDS bf16 (shared across waves)
//     K: k-GEMM (MFMA) -> k held in 28 packed-bf16 VGPRs; hdot/tdot fused MFMA
//     T: barrier; overlay same LDS as kT[j][e_l]; unconditional b16 stores
//        (bijection f=200e+j; garbage rows (>=100) land exactly in pad cols 64..71)
//     S: scores = q-slice x kT rows via MFMA
//  F: sum halves, masked exp, beta=0.5 norm, pred, sigmoid

#define HH 200
#define EE 128
#define KT_PITCH 72   // u16/row = 144 B (16B-aligned rows); store banks (4j+g) mod 32 = 2-way

typedef float fp32x4 __attribute__((ext_vector_type(4)));
typedef short bf16x8 __attribute__((ext_vector_type(8)));

static __device__ __forceinline__ unsigned short f2bf(float x) {
    unsigned u = __builtin_bit_cast(unsigned, x);
    unsigned r = (u + 0x7FFFu + ((u >> 16) & 1u)) >> 16;   // RNE
    return (unsigned short)r;
}

// ---------------- Kernel prep: table conversion + q/u/targ projection ----------------
#define N4_T 1600000   // embT float4 units (100000*64/4)
#define N4_R 16000     // embR
#define N4_K 4096      // Wk
#define N4_ALL (N4_T + N4_R + N4_K)
#define CONV_BLOCKS 2048
#define CONV_THREADS (CONV_BLOCKS * 256)

__global__ __launch_bounds__(256) void prep(
    const int* __restrict__ target, const int* __restrict__ tregion,
    const float* __restrict__ embT, const float* __restrict__ embR,
    const float* __restrict__ Wq, const float* __restrict__ Wk,
    const float* __restrict__ Wv,
    unsigned short* __restrict__ dT, unsigned short* __restrict__ dR,
    unsigned short* __restrict__ dK,
    unsigned short* __restrict__ qbf, unsigned short* __restrict__ ubf,
    unsigned short* __restrict__ tbf)
{
    const int tid = threadIdx.x;
    if (blockIdx.x < CONV_BLOCKS) {
        int idx = blockIdx.x * 256 + tid;
        for (int i = idx; i < N4_ALL; i += CONV_THREADS) {
            const float* src; unsigned short* dst;
            if (i < N4_T)             { src = embT + 4*(size_t)i;            dst = dT + 4*(size_t)i; }
            else if (i < N4_T + N4_R) { int j = i - N4_T;        src = embR + 4*(size_t)j; dst = dR + 4*(size_t)j; }
            else                      { int j = i - N4_T - N4_R; src = Wk   + 4*(size_t)j; dst = dK + 4*(size_t)j; }
            float4 v = *(const float4*)src;
            ushort4 o;
            o.x = f2bf(v.x); o.y = f2bf(v.y); o.z = f2bf(v.z); o.w = f2bf(v.w);
            *(ushort4*)dst = o;
        }
        return;
    }

    // projection role: 8 batches per block
    __shared__ float st[8][128];
    const int b0 = (blockIdx.x - CONV_BLOCKS) * 8;

    if (tid < 128) {
        int bb = tid >> 4, j = tid & 15;
        int b = b0 + bb;
        int ti = target[b], ri = tregion[b];
        *(float4*)&st[bb][j*4]      = *(const float4*)(embT + (size_t)ti*64 + j*4);
        *(float4*)&st[bb][64+j*4]   = *(const float4*)(embR + (size_t)ri*64 + j*4);
    }
    __syncthreads();

    if (tid < 128) {
        float acc[8] = {0,0,0,0,0,0,0,0};
        const float4* wr = (const float4*)(Wq + (size_t)tid*128);
        for (int e4 = 0; e4 < 32; e4++) {
            float4 w4 = wr[e4];
            #pragma unroll
            for (int bb = 0; bb < 8; bb++) {
                float4 t4 = *(const float4*)&st[bb][e4*4];
                acc[bb] += w4.x*t4.x + w4.y*t4.y + w4.z*t4.z + w4.w*t4.w;
            }
        }
        #pragma unroll
        for (int bb = 0; bb < 8; bb++) qbf[(size_t)(b0+bb)*128 + tid] = f2bf(acc[bb]);
    } else {
        int e = tid - 128;
        float acc[8] = {0,0,0,0,0,0,0,0};
        for (int f = 0; f < 128; f++) {
            float wv = Wv[(size_t)f*128 + e];
            #pragma unroll
            for (int bb = 0; bb < 8; bb++) acc[bb] += st[bb][f] * wv;
        }
        #pragma unroll
        for (int bb = 0; bb < 8; bb++) ubf[(size_t)(b0+bb)*128 + e] = f2bf(acc[bb]);
    }
    __syncthreads();
    {
        int bb = tid >> 5, x = (tid & 31) * 4;
        float4 t4 = *(const float4*)&st[bb][x];
        ushort4 o; o.x = f2bf(t4.x); o.y = f2bf(t4.y); o.z = f2bf(t4.z); o.w = f2bf(t4.w);
        *(ushort4*)&tbf[(size_t)(b0+bb)*128 + x] = o;
    }
}

// ---------------- Kernel B: staged gather + k-in-regs + LDS overlay kT ----------------
// grid 4096: b = bid>>1, hf = bid&1.  LDS = 28.8 KB; VGPR<=128 -> 4 blocks/CU.
__global__ __launch_bounds__(256, 4) void hist_gemm(
    const int* __restrict__ history, const int* __restrict__ hregion,
    const unsigned short* __restrict__ eT, const unsigned short* __restrict__ eR,
    const unsigned short* __restrict__ wk, const unsigned short* __restrict__ qb,
    const unsigned short* __restrict__ ub, const unsigned short* __restrict__ tb,
    float* __restrict__ scores_p, float* __restrict__ hdot, float* __restrict__ tdot)
{
    // phase G/K: hist[112][128] bf16, XOR-swizzled 256B rows (28672 B)
    // phase T/S: kT[200][KT_PITCH] bf16 (28800 B) -- same memory, after barrier
    __shared__ unsigned short smem[200 * KT_PITCH];

    const int bid = blockIdx.x;
    const int b = bid >> 1, hf = bid & 1;
    const int tid = threadIdx.x;
    const int lane = tid & 63, w = tid >> 6;
    const int c = lane & 15, g = lane >> 4;
    const int e0 = 8 * g;
    const int rbase = hf * 100;

    // Wk B-fragments: wave w owns k-columns h in [32w, 32w+32)
    bf16x8 wkf[2][4];
    #pragma unroll
    for (int nt = 0; nt < 2; nt++)
        #pragma unroll
        for (int kc = 0; kc < 4; kc++)
            wkf[nt][kc] = *(const bf16x8*)(wk + (size_t)(32*w + 16*nt + c)*128 + kc*32 + e0);

    // ---- Phase G: gather 112 clamped rows (7 iters x 256 threads, exact fill) ----
    #pragma unroll
    for (int it = 0; it < 7; it++) {
        int r = it*16 + (tid >> 4);
        int j = tid & 15;
        int rr = (r < 100) ? r : 99;                // clamp: rows 100..111 duplicate row 99
        size_t rg = (size_t)b*200 + rbase + rr;
        const unsigned short* src;
        if (j < 8) { int ih = history[rg]; src = eT + (size_t)ih*64 + j*8; }
        else       { int ir = hregion[rg]; src = eR + (size_t)ir*64 + (j-8)*8; }
        unsigned dst = ((unsigned)(r*256 + j*16)) ^ (((unsigned)(r & 7)) << 4);
        *(uint4*)((char*)smem + dst) = *(const uint4*)src;
    }
    __syncthreads();

    // ---- Phase K: 7 uniform m-tiles; k kept in 28 packed-bf16 VGPRs ----
    unsigned kv32[28];
    #pragma unroll
    for (int mt = 0; mt < 7; mt++) {
        const int ar = mt*16 + c;
        const unsigned swa = ((unsigned)(ar & 7)) << 4;
        bf16x8 a[4];
        #pragma unroll
        for (int kc = 0; kc < 4; kc++) {
            unsigned off = ((unsigned)(ar*256 + kc*64 + e0*2)) ^ swa;
            a[kc] = *(const bf16x8*)((const char*)smem + off);
        }
        fp32x4 acc0 = {0,0,0,0}, acc1 = {0,0,0,0};
        #pragma unroll
        for (int kc = 0; kc < 4; kc++) {
            acc0 = __builtin_amdgcn_mfma_f32_16x16x32_bf16(a[kc], wkf[0][kc], acc0, 0, 0, 0);
            acc1 = __builtin_amdgcn_mfma_f32_16x16x32_bf16(a[kc], wkf[1][kc], acc1, 0, 0, 0);
        }
        #pragma unroll
        for (int r = 0; r < 4; r++)
            kv32[mt*4 + r] = (unsigned)f2bf(acc0[r]) | ((unsigned)f2bf(acc1[r]) << 16);

        // fused hdot/tdot: extra MFMA vs [u|t] packed B (cols 0-7=u, 8-15=t)
        if ((mt & 3) == w) {
            const unsigned short* utp = (c < 8 ? ub : tb) + (size_t)b*128;
            fp32x4 hacc = {0,0,0,0};
            #pragma unroll
            for (int kc = 0; kc < 4; kc++) {
                bf16x8 utf = *(const bf16x8*)(utp + kc*32 + e0);
                hacc = __builtin_amdgcn_mfma_f32_16x16x32_bf16(a[kc], utf, hacc, 0, 0, 0);
            }
            if (c == 0 || c == 8) {
                float* dst = (c == 0) ? hdot : tdot;
                const int slb = mt*16 + 4*g;
                #pragma unroll
                for (int r = 0; r < 4; r++) {
                    int sl = slb + r;
                    if (sl < 100) dst[(size_t)b*200 + rbase + sl] = hacc[r];
                }
            }
        }
    }
    __syncthreads();   // hist tile fully consumed; smem becomes kT

    // ---- Phase T: unconditional kT stores (garbage rows land in pad cols) ----
    #pragma unroll
    for (int mt = 0; mt < 7; mt++) {
        const int slb = mt*16 + 4*g;
        #pragma unroll
        for (int r = 0; r < 4; r++) {
            unsigned v = kv32[mt*4 + r];
            unsigned f  = (unsigned)((rbase + slb + r)*128 + 32*w + c);
            unsigned e  = f / 200u;  unsigned j  = f - e*200u;
            smem[j*KT_PITCH + (e - (unsigned)(hf<<6))] = (unsigned short)v;
            unsigned f2 = f + 16u;
            unsigned e2 = f2 / 200u; unsigned j2 = f2 - e2*200u;
            smem[j2*KT_PITCH + (e2 - (unsigned)(hf<<6))] = (unsigned short)(v >> 16);
        }
    }
    __syncthreads();

    // ---- Phase S: scores = q-slice x kT rows via MFMA; 13 j-tiles round-robin ----
    for (int jt = w; jt < 13; jt += 4) {
        int jr = jt*16 + c; if (jr > 199) jr = 199;   // pad rows discarded below
        fp32x4 sacc = {0,0,0,0};
        #pragma unroll
        for (int kc = 0; kc < 2; kc++) {
            bf16x8 af  = *(const bf16x8*)(qb + (size_t)b*128 + (hf<<6) + kc*32 + e0);
            bf16x8 bfr = *(const bf16x8*)&smem[(unsigned)jr*KT_PITCH + kc*32 + e0];
            sacc = __builtin_amdgcn_mfma_f32_16x16x32_bf16(af, bfr, sacc, 0, 0, 0);
        }
        if (lane < 16) {
            int j = jt*16 + lane;
            if (j < 200) scores_p[(size_t)bid*200 + j] = sacc[0];
        }
    }
}

// ---------------- Kernel F: finalize (8 batches/block) ----------------
__global__ __launch_bounds__(256) void finalize_k(
    const int* __restrict__ history, const int* __restrict__ target,
    const float* __restrict__ hvr,
    const float* __restrict__ scores_p, const float* __restrict__ hdot,
    const float* __restrict__ tdot, float* __restrict__ out)
{
    const int tid = threadIdx.x, lane = tid & 63, w = tid >> 6;
    #pragma unroll
    for (int bb = 0; bb < 2; bb++) {
        int b = blockIdx.x*8 + w*2 + bb;
        int tgt = target[b];
        float ev[4], hd[4], td[4], hv[4];
        #pragma unroll
        for (int i = 0; i < 4; i++) {
            int j = lane + i*64;
            if (j < 200) {
                float sc = scores_p[(size_t)(2*b)*200 + j] + scores_p[(size_t)(2*b+1)*200 + j];
                int uh = history[(size_t)b*200 + j];
                ev[i] = (uh != tgt) ? expf(sc * 0.088388347648318447f) : 0.f;
                hd[i] = hdot[(size_t)b*200 + j];
                td[i] = tdot[(size_t)b*200 + j];
                hv[i] = hvr[j];
            } else { ev[i] = 0.f; hd[i] = 0.f; td[i] = 0.f; hv[i] = 0.f; }
        }
        float tot = (ev[0]+ev[1]) + (ev[2]+ev[3]);
        #pragma unroll
        for (int m = 1; m < 64; m <<= 1) tot += __shfl_xor(tot, m, 64);
        float inv = rsqrtf(tot);          // exp_A / sum^0.5
        float p = 0.f;
        #pragma unroll
        for (int i = 0; i < 4; i++) p += ev[i]*inv*hd[i] + hv[i]*td[i];
        #pragma unroll
        for (int m = 1; m < 64; m <<= 1) p += __shfl_xor(p, m, 64);
        if (lane == 0) out[b] = 1.0f / (1.0f + expf(-p));
    }
}

extern "C" void kernel_launch(void* const* d_in, const int* in_sizes, int n_in,
                              void* d_out, int out_size, void* d_ws, size_t ws_size,
                              hipStream_t stream) {
    const int*   history = (const int*)d_in[0];
    const int*   target  = (const int*)d_in[1];
    const int*   hregion = (const int*)d_in[2];
    const int*   tregion = (const int*)d_in[3];
    const float* hvrate  = (const float*)d_in[4];
    const float* embT    = (const float*)d_in[5];
    const float* embR    = (const float*)d_in[6];
    const float* Wq      = (const float*)d_in[7];
    const float* Wk      = (const float*)d_in[8];
    const float* Wv      = (const float*)d_in[9];
    float* outp = (float*)d_out;

    char* ws = (char*)d_ws;
    unsigned short* dT = (unsigned short*)(ws);                 // 12,800,000 B
    unsigned short* dR = (unsigned short*)(ws + 12800000);      //    128,000
    unsigned short* dK = (unsigned short*)(ws + 12928000);      //     32,768
    unsigned short* ub = (unsigned short*)(ws + 12960768);      //    524,288
    unsigned short* tb = (unsigned short*)(ws + 13485056);      //    524,288
    unsigned short* qb = (unsigned short*)(ws + 14009344);      //    524,288
    float* sp          = (float*)(ws + 14533632);               //  3,276,800
    float* hdp         = (float*)(ws + 17810432);               //  1,638,400
    float* tdp         = (float*)(ws + 19448832);               //  1,638,400  (end 21,087,232)

    hipLaunchKernelGGL(prep, dim3(CONV_BLOCKS + 256), dim3(256), 0, stream,
                       target, tregion, embT, embR, Wq, Wk, Wv,
                       dT, dR, dK, qb, ub, tb);
    hipLaunchKernelGGL(hist_gemm, dim3(4096), dim3(256), 0, stream,
                       history, hregion, dT, dR, dK, qb, ub, tb, sp, hdp, tdp);
    hipLaunchKernelGGL(finalize_k, dim3(256), dim3(256), 0, stream,
                       history, target, hvrate, sp, hdp, tdp, outp);
}